// Round 2
// baseline (878.283 us; speedup 1.0000x reference)
//
#include <hip/hip_runtime.h>
#include <stdint.h>

#define Bb 4
#define Ss 2048
#define Ee 1024
#define Hh 16
#define Dd 64
#define Wwin 256
#define Mrows 8192

typedef __attribute__((ext_vector_type(8))) short short8;
typedef __attribute__((ext_vector_type(4))) short short4v;
typedef __attribute__((ext_vector_type(4))) float f32x4;

__device__ __forceinline__ short f2bf(float f) {
  unsigned int u = __float_as_uint(f);
  u = u + 0x7fffu + ((u >> 16) & 1u);
  return (short)(u >> 16);
}
__device__ __forceinline__ float bf2f(short s) {
  return __uint_as_float(((unsigned int)(unsigned short)s) << 16);
}

// ---------------- LayerNorm: x[8192][1024] f32 -> xn bf16 ----------------
__global__ __launch_bounds__(256) void ln_kernel(const float* __restrict__ x,
                                                 const float* __restrict__ gam,
                                                 const float* __restrict__ bet,
                                                 short* __restrict__ xn) {
  int row = blockIdx.x;
  int tid = threadIdx.x;
  const float4* xr = (const float4*)(x + (size_t)row * Ee);
  float4 xv = xr[tid];
  float s1 = xv.x + xv.y + xv.z + xv.w;
  float s2 = xv.x * xv.x + xv.y * xv.y + xv.z * xv.z + xv.w * xv.w;
  for (int o = 32; o; o >>= 1) { s1 += __shfl_down(s1, o); s2 += __shfl_down(s2, o); }
  __shared__ float red[8];
  int wid = tid >> 6, lane = tid & 63;
  if (lane == 0) { red[wid] = s1; red[4 + wid] = s2; }
  __syncthreads();
  s1 = red[0] + red[1] + red[2] + red[3];
  s2 = red[4] + red[5] + red[6] + red[7];
  float mean = s1 * (1.0f / Ee);
  float var = s2 * (1.0f / Ee) - mean * mean;
  float rstd = rsqrtf(var + 1e-12f);
  float4 gv = ((const float4*)gam)[tid];
  float4 bv = ((const float4*)bet)[tid];
  short4v o;
  o.x = f2bf((xv.x - mean) * rstd * gv.x + bv.x);
  o.y = f2bf((xv.y - mean) * rstd * gv.y + bv.y);
  o.z = f2bf((xv.z - mean) * rstd * gv.z + bv.z);
  o.w = f2bf((xv.w - mean) * rstd * gv.w + bv.w);
  *(short4v*)(xn + (size_t)row * Ee + tid * 4) = o;
}

// ---------------- weight f32 -> bf16 ----------------
__global__ __launch_bounds__(256) void wcvt_kernel(const float* __restrict__ w,
                                                   short* __restrict__ o) {
  int idx = (blockIdx.x * 256 + threadIdx.x) * 8;
  float4 a = *(const float4*)(w + idx);
  float4 b = *(const float4*)(w + idx + 4);
  short8 r;
  r[0] = f2bf(a.x); r[1] = f2bf(a.y); r[2] = f2bf(a.z); r[3] = f2bf(a.w);
  r[4] = f2bf(b.x); r[5] = f2bf(b.y); r[6] = f2bf(b.z); r[7] = f2bf(b.w);
  *(short8*)(o + idx) = r;
}

// ---------------- GEMM mainloop (m97-style 128x128, BK=32) ----------------
__device__ __forceinline__ void glds16(const short* g, short* l) {
  __builtin_amdgcn_global_load_lds((const __attribute__((address_space(1))) unsigned int*)g,
                                   (__attribute__((address_space(3))) unsigned int*)l, 16, 0, 0);
}

// C = A[128 rows m0..] * W^T (W row-major [N][K]); both bf16, K=1024
__device__ __forceinline__ void gemm_main(const short* __restrict__ A,
                                          const short* __restrict__ Wp,
                                          int m0, int n0,
                                          short* As, short* Bs, f32x4 acc[4][4]) {
  int tid = threadIdx.x;
  int wid = tid >> 6, lane = tid & 63;
  int wm = wid >> 1, wn = wid & 1;
  int r = lane & 15, g4 = lane >> 4;
  int rowS = tid >> 2;
  int kc = (tid & 3) * 8;
  const short* ga = A + (size_t)(m0 + rowS) * Ee + kc;
  const short* gb = Wp + (size_t)(n0 + rowS) * Ee + kc;
  short* lA = As + wid * 512;
  short* lB = Bs + wid * 512;
  for (int k0 = 0; k0 < Ee; k0 += 32) {
    glds16(ga + k0, lA);
    glds16(ga + (size_t)64 * Ee + k0, lA + 2048);
    glds16(gb + k0, lB);
    glds16(gb + (size_t)64 * Ee + k0, lB + 2048);
    __syncthreads();
    short8 af[4], bfr[4];
#pragma unroll
    for (int mi = 0; mi < 4; ++mi)
      af[mi] = *(const short8*)&As[(wm * 64 + mi * 16 + r) * 32 + g4 * 8];
#pragma unroll
    for (int ni = 0; ni < 4; ++ni)
      bfr[ni] = *(const short8*)&Bs[(wn * 64 + ni * 16 + r) * 32 + g4 * 8];
#pragma unroll
    for (int mi = 0; mi < 4; ++mi)
#pragma unroll
      for (int ni = 0; ni < 4; ++ni)
        acc[mi][ni] = __builtin_amdgcn_mfma_f32_16x16x32_bf16(af[mi], bfr[ni], acc[mi][ni], 0, 0, 0);
    __syncthreads();
  }
}

// ---------------- QKV GEMM: grid 64 x 24 (3 weights x 8 col-blocks) ----------------
__global__ __launch_bounds__(256) void qkv_gemm(const short* __restrict__ xn,
                                                const short* __restrict__ wb,
                                                const float* __restrict__ bq,
                                                const float* __restrict__ bk,
                                                const float* __restrict__ bv,
                                                short* __restrict__ q,
                                                short* __restrict__ k,
                                                short* __restrict__ v) {
  __shared__ short As[128 * 32];
  __shared__ short Bs[128 * 32];
  int bid = blockIdx.x;                    // 1536 = 8*192
  int swz = (bid & 7) * 192 + (bid >> 3);
  int nb = swz % 24, mb = swz / 24;
  int m0 = mb * 128;
  int w = nb >> 3;
  int n0 = (nb & 7) * 128;
  const short* Wp = wb + (size_t)w * (Ee * Ee);
  f32x4 acc[4][4];
#pragma unroll
  for (int i = 0; i < 4; ++i)
#pragma unroll
    for (int j = 0; j < 4; ++j) acc[i][j] = (f32x4){0.f, 0.f, 0.f, 0.f};
  gemm_main(xn, Wp, m0, n0, As, Bs, acc);
  const float* bias = (w == 0) ? bq : (w == 1) ? bk : bv;
  short* dst = (w == 0) ? q : (w == 1) ? k : v;
  int tid = threadIdx.x;
  int wid = tid >> 6, lane = tid & 63;
  int wm = wid >> 1, wn = wid & 1;
  int r = lane & 15, g4 = lane >> 4;
#pragma unroll
  for (int mi = 0; mi < 4; ++mi)
#pragma unroll
    for (int ni = 0; ni < 4; ++ni) {
      int col = n0 + wn * 64 + ni * 16 + r;
      float bcol = bias[col];
#pragma unroll
      for (int i2 = 0; i2 < 4; ++i2) {
        int grow = m0 + wm * 64 + mi * 16 + g4 * 4 + i2;
        dst[(size_t)grow * Ee + col] = f2bf(acc[mi][ni][i2] + bcol);
      }
    }
}

// ---------------- Output GEMM + bias + residual ----------------
__global__ __launch_bounds__(256) void out_gemm(const short* __restrict__ ctx,
                                                const short* __restrict__ wo,
                                                const float* __restrict__ bo,
                                                const float* __restrict__ xres,
                                                float* __restrict__ out) {
  __shared__ short As[128 * 32];
  __shared__ short Bs[128 * 32];
  int bid = blockIdx.x;                    // 512 = 8*64
  int swz = (bid & 7) * 64 + (bid >> 3);
  int nb = swz & 7, mb = swz >> 3;
  int m0 = mb * 128, n0 = nb * 128;
  f32x4 acc[4][4];
#pragma unroll
  for (int i = 0; i < 4; ++i)
#pragma unroll
    for (int j = 0; j < 4; ++j) acc[i][j] = (f32x4){0.f, 0.f, 0.f, 0.f};
  gemm_main(ctx, wo, m0, n0, As, Bs, acc);
  int tid = threadIdx.x;
  int wid = tid >> 6, lane = tid & 63;
  int wm = wid >> 1, wn = wid & 1;
  int r = lane & 15, g4 = lane >> 4;
#pragma unroll
  for (int mi = 0; mi < 4; ++mi)
#pragma unroll
    for (int ni = 0; ni < 4; ++ni) {
      int col = n0 + wn * 64 + ni * 16 + r;
      float bcol = bo[col];
#pragma unroll
      for (int i2 = 0; i2 < 4; ++i2) {
        int grow = m0 + wm * 64 + mi * 16 + g4 * 4 + i2;
        size_t off = (size_t)grow * Ee + col;
        out[off] = acc[mi][ni][i2] + bcol + xres[off];
      }
    }
}

// ---------------- sliding-window attention (VALU, round 0) ----------------
// one wave per query row; block = 4 consecutive rows of one (b,h)
__global__ __launch_bounds__(256) void attn_kernel(const short* __restrict__ Q,
                                                   const short* __restrict__ K,
                                                   const short* __restrict__ V,
                                                   short* __restrict__ ctx) {
  __shared__ float qbuf[4][64];
  __shared__ float pbuf[4][256];
  int bid = blockIdx.x;                    // 32768 = 8*4096
  int swz = (bid & 7) * 4096 + (bid >> 3);
  int p = swz >> 9;                        // (b,h) pair
  int t = swz & 511;                       // row-group within pair
  int b = p >> 4, h = p & 15;
  int wid = threadIdx.x >> 6, lane = threadIdx.x & 63;
  int i = t * 4 + wid;
  size_t headoff = (size_t)b * Ss * Ee + (size_t)h * Dd;
  const short* Qrow = Q + headoff + (size_t)i * Ee;
  qbuf[wid][lane] = bf2f(Qrow[lane]) * 0.125f;  // fold 1/sqrt(D)
  __syncthreads();
  int jstart = i - (Wwin - 1); if (jstart < 0) jstart = 0;
  int nk = i - jstart + 1;
  const short* Kbase = K + headoff + (size_t)jstart * Ee;

  float sc[4] = {-1e30f, -1e30f, -1e30f, -1e30f};
#pragma unroll
  for (int c = 0; c < 4; ++c)
    if (lane + 64 * c < nk) sc[c] = 0.0f;

  for (int ch = 0; ch < 8; ++ch) {
    float4 qa = *(const float4*)&qbuf[wid][ch * 8];
    float4 qb2 = *(const float4*)&qbuf[wid][ch * 8 + 4];
#pragma unroll
    for (int c = 0; c < 4; ++c) {
      int j = lane + 64 * c;
      if (j < nk) {
        uint4 kv = *(const uint4*)(Kbase + (size_t)j * Ee + ch * 8);
        float f0 = __uint_as_float(kv.x << 16);
        float f1 = __uint_as_float(kv.x & 0xffff0000u);
        float f2 = __uint_as_float(kv.y << 16);
        float f3 = __uint_as_float(kv.y & 0xffff0000u);
        float f4 = __uint_as_float(kv.z << 16);
        float f5 = __uint_as_float(kv.z & 0xffff0000u);
        float f6 = __uint_as_float(kv.w << 16);
        float f7 = __uint_as_float(kv.w & 0xffff0000u);
        float s = sc[c];
        s = fmaf(f0, qa.x, s);  s = fmaf(f1, qa.y, s);
        s = fmaf(f2, qa.z, s);  s = fmaf(f3, qa.w, s);
        s = fmaf(f4, qb2.x, s); s = fmaf(f5, qb2.y, s);
        s = fmaf(f6, qb2.z, s); s = fmaf(f7, qb2.w, s);
        sc[c] = s;
      }
    }
  }
  float m = fmaxf(fmaxf(sc[0], sc[1]), fmaxf(sc[2], sc[3]));
  for (int o = 32; o; o >>= 1) m = fmaxf(m, __shfl_xor(m, o));
  float pr[4]; float l = 0.f;
#pragma unroll
  for (int c = 0; c < 4; ++c) {
    int j = lane + 64 * c;
    pr[c] = (j < nk) ? __expf(sc[c] - m) : 0.0f;
    l += pr[c];
  }
  for (int o = 32; o; o >>= 1) l += __shfl_xor(l, o);
  float rl = 1.0f / l;
#pragma unroll
  for (int c = 0; c < 4; ++c) pbuf[wid][lane + 64 * c] = pr[c] * rl;
  __syncthreads();

  const short* Vbase = V + headoff + (size_t)jstart * Ee + lane;
  float acc = 0.f;
#pragma unroll 4
  for (int j = 0; j < nk; ++j)
    acc = fmaf(pbuf[wid][j], bf2f(Vbase[(size_t)j * Ee]), acc);
  ctx[headoff + (size_t)i * Ee + lane] = f2bf(acc);
}

extern "C" void kernel_launch(void* const* d_in, const int* in_sizes, int n_in,
                              void* d_out, int out_size, void* d_ws, size_t ws_size,
                              hipStream_t stream) {
  const float* x    = (const float*)d_in[0];
  const float* ln_g = (const float*)d_in[1];
  const float* ln_b = (const float*)d_in[2];
  const float* w_q  = (const float*)d_in[3];
  const float* b_q  = (const float*)d_in[4];
  const float* w_k  = (const float*)d_in[5];
  const float* b_k  = (const float*)d_in[6];
  const float* w_v  = (const float*)d_in[7];
  const float* b_v  = (const float*)d_in[8];
  const float* w_o  = (const float*)d_in[9];
  const float* b_o  = (const float*)d_in[10];
  float* out = (float*)d_out;
  char* ws = (char*)d_ws;
  short* xn = (short*)(ws);                       // 16MB; reused as ctx after qkv
  short* qb = (short*)(ws + ((size_t)16 << 20));
  short* kb = (short*)(ws + ((size_t)32 << 20));
  short* vb = (short*)(ws + ((size_t)48 << 20));
  short* wb = (short*)(ws + ((size_t)64 << 20));  // 4 x 2MB bf16 weights

  ln_kernel<<<Mrows, 256, 0, stream>>>(x, ln_g, ln_b, xn);
  wcvt_kernel<<<512, 256, 0, stream>>>(w_q, wb + 0 * 1048576);
  wcvt_kernel<<<512, 256, 0, stream>>>(w_k, wb + 1 * 1048576);
  wcvt_kernel<<<512, 256, 0, stream>>>(w_v, wb + 2 * 1048576);
  wcvt_kernel<<<512, 256, 0, stream>>>(w_o, wb + 3 * 1048576);
  qkv_gemm<<<1536, 256, 0, stream>>>(xn, wb, b_q, b_k, b_v, qb, kb, vb);
  attn_kernel<<<32768, 256, 0, stream>>>(qb, kb, vb, xn /*ctx*/);
  out_gemm<<<512, 256, 0, stream>>>(xn /*ctx*/, wb + 3 * 1048576, b_o, x, out);
}

// Round 4
// 288.605 us; speedup vs baseline: 3.0432x; 3.0432x over previous
//
#include <hip/hip_runtime.h>
#include <stdint.h>

#define Bb 4
#define Ss 2048
#define Ee 1024
#define Hh 16
#define Dd 64
#define Wwin 256
#define Mrows 8192

typedef __attribute__((ext_vector_type(8))) short short8;
typedef __attribute__((ext_vector_type(4))) short short4v;
typedef __attribute__((ext_vector_type(4))) float f32x4;

__device__ __forceinline__ short f2bf(float f) {
  unsigned int u = __float_as_uint(f);
  u = u + 0x7fffu + ((u >> 16) & 1u);
  return (short)(u >> 16);
}
__device__ __forceinline__ float bf2f(short s) {
  return __uint_as_float(((unsigned int)(unsigned short)s) << 16);
}

// ---------------- LayerNorm: x[8192][1024] f32 -> xn bf16 ----------------
__global__ __launch_bounds__(256) void ln_kernel(const float* __restrict__ x,
                                                 const float* __restrict__ gam,
                                                 const float* __restrict__ bet,
                                                 short* __restrict__ xn) {
  int row = blockIdx.x;
  int tid = threadIdx.x;
  const float4* xr = (const float4*)(x + (size_t)row * Ee);
  float4 xv = xr[tid];
  float s1 = xv.x + xv.y + xv.z + xv.w;
  float s2 = xv.x * xv.x + xv.y * xv.y + xv.z * xv.z + xv.w * xv.w;
  for (int o = 32; o; o >>= 1) { s1 += __shfl_down(s1, o); s2 += __shfl_down(s2, o); }
  __shared__ float red[8];
  int wid = tid >> 6, lane = tid & 63;
  if (lane == 0) { red[wid] = s1; red[4 + wid] = s2; }
  __syncthreads();
  s1 = red[0] + red[1] + red[2] + red[3];
  s2 = red[4] + red[5] + red[6] + red[7];
  float mean = s1 * (1.0f / Ee);
  float var = s2 * (1.0f / Ee) - mean * mean;
  float rstd = rsqrtf(var + 1e-12f);
  float4 gv = ((const float4*)gam)[tid];
  float4 bv = ((const float4*)bet)[tid];
  short4v o;
  o.x = f2bf((xv.x - mean) * rstd * gv.x + bv.x);
  o.y = f2bf((xv.y - mean) * rstd * gv.y + bv.y);
  o.z = f2bf((xv.z - mean) * rstd * gv.z + bv.z);
  o.w = f2bf((xv.w - mean) * rstd * gv.w + bv.w);
  *(short4v*)(xn + (size_t)row * Ee + tid * 4) = o;
}

// ---------------- weight f32 -> bf16 ----------------
__global__ __launch_bounds__(256) void wcvt_kernel(const float* __restrict__ w,
                                                   short* __restrict__ o) {
  int idx = (blockIdx.x * 256 + threadIdx.x) * 8;
  float4 a = *(const float4*)(w + idx);
  float4 b = *(const float4*)(w + idx + 4);
  short8 r;
  r[0] = f2bf(a.x); r[1] = f2bf(a.y); r[2] = f2bf(a.z); r[3] = f2bf(a.w);
  r[4] = f2bf(b.x); r[5] = f2bf(b.y); r[6] = f2bf(b.z); r[7] = f2bf(b.w);
  *(short8*)(o + idx) = r;
}

// ---------------- GEMM mainloop (m97-style 128x128, BK=32) ----------------
__device__ __forceinline__ void glds16(const short* g, short* l) {
  __builtin_amdgcn_global_load_lds((const __attribute__((address_space(1))) unsigned int*)g,
                                   (__attribute__((address_space(3))) unsigned int*)l, 16, 0, 0);
}

// C = A[128 rows m0..] * W^T (W row-major [N][K]); both bf16, K=1024
__device__ __forceinline__ void gemm_main(const short* __restrict__ A,
                                          const short* __restrict__ Wp,
                                          int m0, int n0,
                                          short* As, short* Bs, f32x4 acc[4][4]) {
  int tid = threadIdx.x;
  int wid = tid >> 6, lane = tid & 63;
  int wm = wid >> 1, wn = wid & 1;
  int r = lane & 15, g4 = lane >> 4;
  int rowS = tid >> 2;
  int kc = (tid & 3) * 8;
  const short* ga = A + (size_t)(m0 + rowS) * Ee + kc;
  const short* gb = Wp + (size_t)(n0 + rowS) * Ee + kc;
  short* lA = As + wid * 512;
  short* lB = Bs + wid * 512;
  for (int k0 = 0; k0 < Ee; k0 += 32) {
    glds16(ga + k0, lA);
    glds16(ga + (size_t)64 * Ee + k0, lA + 2048);
    glds16(gb + k0, lB);
    glds16(gb + (size_t)64 * Ee + k0, lB + 2048);
    __syncthreads();
    short8 af[4], bfr[4];
#pragma unroll
    for (int mi = 0; mi < 4; ++mi)
      af[mi] = *(const short8*)&As[(wm * 64 + mi * 16 + r) * 32 + g4 * 8];
#pragma unroll
    for (int ni = 0; ni < 4; ++ni)
      bfr[ni] = *(const short8*)&Bs[(wn * 64 + ni * 16 + r) * 32 + g4 * 8];
#pragma unroll
    for (int mi = 0; mi < 4; ++mi)
#pragma unroll
      for (int ni = 0; ni < 4; ++ni)
        acc[mi][ni] = __builtin_amdgcn_mfma_f32_16x16x32_bf16(af[mi], bfr[ni], acc[mi][ni], 0, 0, 0);
    __syncthreads();
  }
}

// ---------------- QKV GEMM: Q,K row-major; V written transposed [B,H,D,S] ----------------
__global__ __launch_bounds__(256) void qkv_gemm(const short* __restrict__ xn,
                                                const short* __restrict__ wb,
                                                const float* __restrict__ bq,
                                                const float* __restrict__ bk,
                                                const float* __restrict__ bv,
                                                short* __restrict__ q,
                                                short* __restrict__ k,
                                                short* __restrict__ vt) {
  __shared__ short As[128 * 32];
  __shared__ short Bs[128 * 32];
  int bid = blockIdx.x;                    // 1536 = 8*192
  int swz = (bid & 7) * 192 + (bid >> 3);
  int nb = swz % 24, mb = swz / 24;
  int m0 = mb * 128;
  int w = nb >> 3;
  int n0 = (nb & 7) * 128;
  const short* Wp = wb + (size_t)w * (Ee * Ee);
  f32x4 acc[4][4];
#pragma unroll
  for (int i = 0; i < 4; ++i)
#pragma unroll
    for (int j = 0; j < 4; ++j) acc[i][j] = (f32x4){0.f, 0.f, 0.f, 0.f};
  gemm_main(xn, Wp, m0, n0, As, Bs, acc);
  const float* bias = (w == 0) ? bq : (w == 1) ? bk : bv;
  int tid = threadIdx.x;
  int wid = tid >> 6, lane = tid & 63;
  int wm = wid >> 1, wn = wid & 1;
  int r = lane & 15, g4 = lane >> 4;
  if (w == 2) {
    // transposed store: vt[((b*16+h)*64+d)][s] where col = h*64+d, b = row>>11, s = row&2047
#pragma unroll
    for (int mi = 0; mi < 4; ++mi)
#pragma unroll
      for (int ni = 0; ni < 4; ++ni) {
        int col = n0 + wn * 64 + ni * 16 + r;
        float bcol = bias[col];
        int grow0 = m0 + wm * 64 + mi * 16 + g4 * 4;
        short4v pk;
        pk.x = f2bf(acc[mi][ni][0] + bcol);
        pk.y = f2bf(acc[mi][ni][1] + bcol);
        pk.z = f2bf(acc[mi][ni][2] + bcol);
        pk.w = f2bf(acc[mi][ni][3] + bcol);
        size_t vbase = ((size_t)(grow0 >> 11) * 1024 + col) * Ss + (grow0 & 2047);
        *(short4v*)(vt + vbase) = pk;
      }
  } else {
    short* dst = (w == 0) ? q : k;
    float qs = (w == 0) ? 0.125f : 1.0f;   // fold 1/sqrt(D) into Q
#pragma unroll
    for (int mi = 0; mi < 4; ++mi)
#pragma unroll
      for (int ni = 0; ni < 4; ++ni) {
        int col = n0 + wn * 64 + ni * 16 + r;
        float bcol = bias[col];
#pragma unroll
        for (int i2 = 0; i2 < 4; ++i2) {
          int grow = m0 + wm * 64 + mi * 16 + g4 * 4 + i2;
          dst[(size_t)grow * Ee + col] = f2bf((acc[mi][ni][i2] + bcol) * qs);
        }
      }
  }
}

// ---------------- Output GEMM + bias + residual ----------------
__global__ __launch_bounds__(256) void out_gemm(const short* __restrict__ ctx,
                                                const short* __restrict__ wo,
                                                const float* __restrict__ bo,
                                                const float* __restrict__ xres,
                                                float* __restrict__ out) {
  __shared__ short As[128 * 32];
  __shared__ short Bs[128 * 32];
  int bid = blockIdx.x;                    // 512 = 8*64
  int swz = (bid & 7) * 64 + (bid >> 3);
  int nb = swz & 7, mb = swz >> 3;
  int m0 = mb * 128, n0 = nb * 128;
  f32x4 acc[4][4];
#pragma unroll
  for (int i = 0; i < 4; ++i)
#pragma unroll
    for (int j = 0; j < 4; ++j) acc[i][j] = (f32x4){0.f, 0.f, 0.f, 0.f};
  gemm_main(ctx, wo, m0, n0, As, Bs, acc);
  int tid = threadIdx.x;
  int wid = tid >> 6, lane = tid & 63;
  int wm = wid >> 1, wn = wid & 1;
  int r = lane & 15, g4 = lane >> 4;
#pragma unroll
  for (int mi = 0; mi < 4; ++mi)
#pragma unroll
    for (int ni = 0; ni < 4; ++ni) {
      int col = n0 + wn * 64 + ni * 16 + r;
      float bcol = bo[col];
#pragma unroll
      for (int i2 = 0; i2 < 4; ++i2) {
        int grow = m0 + wm * 64 + mi * 16 + g4 * 4 + i2;
        size_t off = (size_t)grow * Ee + col;
        out[off] = acc[mi][ni][i2] + bcol + xres[off];
      }
    }
}

// ---------------- sliding-window attention, MFMA (round 2) ----------------
// one wave per 16-row Q-tile; 4 waves/block; K direct from global (L2-resident),
// V from transposed vt[b,h,d,s]; P round-trip through per-wave LDS.
__global__ __launch_bounds__(256) void attn_mfma(const short* __restrict__ Q,
                                                 const short* __restrict__ K,
                                                 const short* __restrict__ vt,
                                                 short* __restrict__ ctx) {
  __shared__ short P_lds[4][16 * 296];     // per-wave [16 q][288 keys + pad]
  int bid = blockIdx.x;                    // 2048
  int swz = (bid & 7) * 256 + (bid >> 3);  // XCD-contiguous
  int bh = swz >> 5;                       // 64 (b,h) pairs
  int tq = swz & 31;
  int b = bh >> 4, h = bh & 15;
  int tid = threadIdx.x;
  int wid = tid >> 6, lane = tid & 63;
  int r = lane & 15, g4 = lane >> 4;
  int q0 = (tq * 4 + wid) * 16;
  short* pl = &P_lds[wid][0];
  f32x4 zero4 = {0.f, 0.f, 0.f, 0.f};

  // Q fragments (scale already folded in)
  size_t qbase = ((size_t)(b * Ss + q0 + r)) * Ee + h * Dd + g4 * 8;
  short8 qf0 = *(const short8*)&Q[qbase];
  short8 qf1 = *(const short8*)&Q[qbase + 32];

  // ---- QK^T over 17 key tiles of 16 (keys q0-256 .. q0+15) ----
  int ktlo = (q0 >= 256) ? 0 : ((256 - q0) >> 4);
  f32x4 sc[17];
#pragma unroll
  for (int kt = 0; kt < 17; ++kt) {
    if (kt >= ktlo) {
      int rowk = q0 - 256 + kt * 16 + r;   // in [0, q0+15] for kt>=ktlo
      size_t koff = ((size_t)(b * Ss + rowk)) * Ee + h * Dd + g4 * 8;
      short8 kf0 = *(const short8*)&K[koff];
      short8 kf1 = *(const short8*)&K[koff + 32];
      f32x4 s = __builtin_amdgcn_mfma_f32_16x16x32_bf16(qf0, kf0, zero4, 0, 0, 0);
      s = __builtin_amdgcn_mfma_f32_16x16x32_bf16(qf1, kf1, s, 0, 0, 0);
      int base = 256 + 4 * g4 - 16 * kt - r;
#pragma unroll
      for (int reg = 0; reg < 4; ++reg) {
        int diff = base + reg;             // i - j
        sc[kt][reg] = ((unsigned)diff < 256u) ? s[reg] : -1e30f;
      }
    } else {
      sc[kt] = (f32x4){-1e30f, -1e30f, -1e30f, -1e30f};
    }
  }

  // ---- softmax over keys (cols = l&15 lanes + tiles) ----
  float mx[4], sm[4];
#pragma unroll
  for (int reg = 0; reg < 4; ++reg) {
    float m = sc[0][reg];
#pragma unroll
    for (int kt = 1; kt < 17; ++kt) m = fmaxf(m, sc[kt][reg]);
    m = fmaxf(m, __shfl_xor(m, 1));
    m = fmaxf(m, __shfl_xor(m, 2));
    m = fmaxf(m, __shfl_xor(m, 4));
    m = fmaxf(m, __shfl_xor(m, 8));
    mx[reg] = m;
    sm[reg] = 0.f;
  }
#pragma unroll
  for (int kt = 0; kt < 17; ++kt)
#pragma unroll
    for (int reg = 0; reg < 4; ++reg) {
      float p = __expf(sc[kt][reg] - mx[reg]);
      sc[kt][reg] = p;
      sm[reg] += p;
    }
#pragma unroll
  for (int reg = 0; reg < 4; ++reg) {
    float s = sm[reg];
    s += __shfl_xor(s, 1); s += __shfl_xor(s, 2);
    s += __shfl_xor(s, 4); s += __shfl_xor(s, 8);
    sm[reg] = 1.0f / s;                    // deferred normalization
  }

  // ---- P -> LDS (A-frag layout [q][key]) ----
#pragma unroll
  for (int kt = 0; kt < 17; ++kt)
#pragma unroll
    for (int reg = 0; reg < 4; ++reg)
      pl[(4 * g4 + reg) * 296 + kt * 16 + r] = f2bf(sc[kt][reg]);
  {                                        // zero pad tile 17 (keys 272..287)
    int zr = lane >> 2, zc = 272 + (lane & 3) * 4;
    *(short4v*)&pl[zr * 296 + zc] = (short4v){0, 0, 0, 0};
  }

  // ---- PV: 9 x 32-key steps, V from vt ----
  f32x4 acc[4];
#pragma unroll
  for (int nt = 0; nt < 4; ++nt) acc[nt] = zero4;
  size_t vtbase = ((size_t)(b * 1024 + h * Dd + r)) * Ss;
#pragma unroll
  for (int s8 = 0; s8 < 9; ++s8) {
    short8 pa = *(const short8*)&pl[r * 296 + s8 * 32 + g4 * 8];
    int tok0 = q0 - 256 + s8 * 32 + g4 * 8;
    tok0 = tok0 < 0 ? 0 : (tok0 > Ss - 8 ? Ss - 8 : tok0);  // P=0 masks OOB
#pragma unroll
    for (int nt = 0; nt < 4; ++nt) {
      short8 vf = *(const short8*)&vt[vtbase + (size_t)nt * 16 * Ss + tok0];
      acc[nt] = __builtin_amdgcn_mfma_f32_16x16x32_bf16(pa, vf, acc[nt], 0, 0, 0);
    }
  }

  // ---- epilogue: normalize, stage in LDS, coalesced store ----
#pragma unroll
  for (int nt = 0; nt < 4; ++nt)
#pragma unroll
    for (int reg = 0; reg < 4; ++reg)
      pl[(4 * g4 + reg) * 72 + nt * 16 + r] = f2bf(acc[nt][reg] * sm[reg]);
  int lr = lane >> 2, lc = (lane & 3) * 16;
  short8 o0 = *(const short8*)&pl[lr * 72 + lc];
  short8 o1 = *(const short8*)&pl[lr * 72 + lc + 8];
  size_t obase = ((size_t)(b * Ss + q0 + lr)) * Ee + h * Dd + lc;
  *(short8*)&ctx[obase] = o0;
  *(short8*)&ctx[obase + 8] = o1;
}

extern "C" void kernel_launch(void* const* d_in, const int* in_sizes, int n_in,
                              void* d_out, int out_size, void* d_ws, size_t ws_size,
                              hipStream_t stream) {
  const float* x    = (const float*)d_in[0];
  const float* ln_g = (const float*)d_in[1];
  const float* ln_b = (const float*)d_in[2];
  const float* w_q  = (const float*)d_in[3];
  const float* b_q  = (const float*)d_in[4];
  const float* w_k  = (const float*)d_in[5];
  const float* b_k  = (const float*)d_in[6];
  const float* w_v  = (const float*)d_in[7];
  const float* b_v  = (const float*)d_in[8];
  const float* w_o  = (const float*)d_in[9];
  const float* b_o  = (const float*)d_in[10];
  float* out = (float*)d_out;
  char* ws = (char*)d_ws;
  short* xn = (short*)(ws);                       // 16MB; reused as ctx after qkv
  short* qb = (short*)(ws + ((size_t)16 << 20));
  short* kb = (short*)(ws + ((size_t)32 << 20));
  short* vt = (short*)(ws + ((size_t)48 << 20));  // V transposed [B,H,D,S]
  short* wb = (short*)(ws + ((size_t)64 << 20));  // 4 x 2MB bf16 weights

  ln_kernel<<<Mrows, 256, 0, stream>>>(x, ln_g, ln_b, xn);
  wcvt_kernel<<<512, 256, 0, stream>>>(w_q, wb + 0 * 1048576);
  wcvt_kernel<<<512, 256, 0, stream>>>(w_k, wb + 1 * 1048576);
  wcvt_kernel<<<512, 256, 0, stream>>>(w_v, wb + 2 * 1048576);
  wcvt_kernel<<<512, 256, 0, stream>>>(w_o, wb + 3 * 1048576);
  qkv_gemm<<<1536, 256, 0, stream>>>(xn, wb, b_q, b_k, b_v, qb, kb, vt);
  attn_mfma<<<2048, 256, 0, stream>>>(qb, kb, vt, xn /*ctx*/);
  out_gemm<<<512, 256, 0, stream>>>(xn /*ctx*/, wb + 3 * 1048576, b_o, x, out);
}

// Round 11
// 283.700 us; speedup vs baseline: 3.0958x; 1.0173x over previous
//
#include <hip/hip_runtime.h>
#include <stdint.h>

#define Bb 4
#define Ss 2048
#define Ee 1024
#define Hh 16
#define Dd 64
#define Wwin 256
#define Mrows 8192

typedef __attribute__((ext_vector_type(8))) short short8;
typedef __attribute__((ext_vector_type(4))) short short4v;
typedef __attribute__((ext_vector_type(4))) float f32x4;

__device__ __forceinline__ short f2bf(float f) {
  unsigned int u = __float_as_uint(f);
  u = u + 0x7fffu + ((u >> 16) & 1u);
  return (short)(u >> 16);
}
__device__ __forceinline__ float bf2f(short s) {
  return __uint_as_float(((unsigned int)(unsigned short)s) << 16);
}

// ---------------- LayerNorm: x[8192][1024] f32 -> xn bf16 ----------------
__global__ __launch_bounds__(256) void ln_kernel(const float* __restrict__ x,
                                                 const float* __restrict__ gam,
                                                 const float* __restrict__ bet,
                                                 short* __restrict__ xn) {
  int row = blockIdx.x;
  int tid = threadIdx.x;
  const float4* xr = (const float4*)(x + (size_t)row * Ee);
  float4 xv = xr[tid];
  float s1 = xv.x + xv.y + xv.z + xv.w;
  float s2 = xv.x * xv.x + xv.y * xv.y + xv.z * xv.z + xv.w * xv.w;
  for (int o = 32; o; o >>= 1) { s1 += __shfl_down(s1, o); s2 += __shfl_down(s2, o); }
  __shared__ float red[8];
  int wid = tid >> 6, lane = tid & 63;
  if (lane == 0) { red[wid] = s1; red[4 + wid] = s2; }
  __syncthreads();
  s1 = red[0] + red[1] + red[2] + red[3];
  s2 = red[4] + red[5] + red[6] + red[7];
  float mean = s1 * (1.0f / Ee);
  float var = s2 * (1.0f / Ee) - mean * mean;
  float rstd = rsqrtf(var + 1e-12f);
  float4 gv = ((const float4*)gam)[tid];
  float4 bv = ((const float4*)bet)[tid];
  short4v o;
  o.x = f2bf((xv.x - mean) * rstd * gv.x + bv.x);
  o.y = f2bf((xv.y - mean) * rstd * gv.y + bv.y);
  o.z = f2bf((xv.z - mean) * rstd * gv.z + bv.z);
  o.w = f2bf((xv.w - mean) * rstd * gv.w + bv.w);
  *(short4v*)(xn + (size_t)row * Ee + tid * 4) = o;
}

// ---------------- all 4 weights f32 -> bf16, one kernel ----------------
__global__ __launch_bounds__(256) void wcvt_all(const float* __restrict__ w0,
                                                const float* __restrict__ w1,
                                                const float* __restrict__ w2,
                                                const float* __restrict__ w3,
                                                short* __restrict__ o) {
  int g = blockIdx.x >> 9;                 // 2048 blocks = 4 x 512
  const float* w = (g == 0) ? w0 : (g == 1) ? w1 : (g == 2) ? w2 : w3;
  int idx = ((blockIdx.x & 511) * 256 + threadIdx.x) * 8;
  float4 a = *(const float4*)(w + idx);
  float4 b = *(const float4*)(w + idx + 4);
  short8 r;
  r[0] = f2bf(a.x); r[1] = f2bf(a.y); r[2] = f2bf(a.z); r[3] = f2bf(a.w);
  r[4] = f2bf(b.x); r[5] = f2bf(b.y); r[6] = f2bf(b.z); r[7] = f2bf(b.w);
  *(short8*)(o + (size_t)g * 1048576 + idx) = r;
}

// ---------------- GEMM mainloop (m97-style 128x128, BK=32) ----------------
__device__ __forceinline__ void glds16(const short* g, short* l) {
  __builtin_amdgcn_global_load_lds((const __attribute__((address_space(1))) unsigned int*)g,
                                   (__attribute__((address_space(3))) unsigned int*)l, 16, 0, 0);
}

// C = A[128 rows m0..] * W^T (W row-major [N][K]); both bf16, K=1024
__device__ __forceinline__ void gemm_main(const short* __restrict__ A,
                                          const short* __restrict__ Wp,
                                          int m0, int n0,
                                          short* As, short* Bs, f32x4 acc[4][4]) {
  int tid = threadIdx.x;
  int wid = tid >> 6, lane = tid & 63;
  int wm = wid >> 1, wn = wid & 1;
  int r = lane & 15, g4 = lane >> 4;
  int rowS = tid >> 2;
  int kc = (tid & 3) * 8;
  const short* ga = A + (size_t)(m0 + rowS) * Ee + kc;
  const short* gb = Wp + (size_t)(n0 + rowS) * Ee + kc;
  short* lA = As + wid * 512;
  short* lB = Bs + wid * 512;
  for (int k0 = 0; k0 < Ee; k0 += 32) {
    glds16(ga + k0, lA);
    glds16(ga + (size_t)64 * Ee + k0, lA + 2048);
    glds16(gb + k0, lB);
    glds16(gb + (size_t)64 * Ee + k0, lB + 2048);
    __syncthreads();
    short8 af[4], bfr[4];
#pragma unroll
    for (int mi = 0; mi < 4; ++mi)
      af[mi] = *(const short8*)&As[(wm * 64 + mi * 16 + r) * 32 + g4 * 8];
#pragma unroll
    for (int ni = 0; ni < 4; ++ni)
      bfr[ni] = *(const short8*)&Bs[(wn * 64 + ni * 16 + r) * 32 + g4 * 8];
#pragma unroll
    for (int mi = 0; mi < 4; ++mi)
#pragma unroll
      for (int ni = 0; ni < 4; ++ni)
        acc[mi][ni] = __builtin_amdgcn_mfma_f32_16x16x32_bf16(af[mi], bfr[ni], acc[mi][ni], 0, 0, 0);
    __syncthreads();
  }
}

// ---------------- QKV GEMM: Q,K row-major (LDS-staged stores); V transposed ----------------
__global__ __launch_bounds__(256) void qkv_gemm(const short* __restrict__ xn,
                                                const short* __restrict__ wb,
                                                const float* __restrict__ bq,
                                                const float* __restrict__ bk,
                                                const float* __restrict__ bv,
                                                short* __restrict__ q,
                                                short* __restrict__ k,
                                                short* __restrict__ vt) {
  __shared__ char LB[34816];               // mainloop: As(8KB)+Bs(8KB); epilogue: 128x136 bf16
  short* As = (short*)LB;
  short* Bs = As + 4096;
  int bid = blockIdx.x;                    // 1536 = 8*192
  int swz = (bid & 7) * 192 + (bid >> 3);
  int nb = swz % 24, mb = swz / 24;
  int m0 = mb * 128;
  int w = nb >> 3;
  int n0 = (nb & 7) * 128;
  const short* Wp = wb + (size_t)w * (Ee * Ee);
  f32x4 acc[4][4];
#pragma unroll
  for (int i = 0; i < 4; ++i)
#pragma unroll
    for (int j = 0; j < 4; ++j) acc[i][j] = (f32x4){0.f, 0.f, 0.f, 0.f};
  gemm_main(xn, Wp, m0, n0, As, Bs, acc);
  const float* bias = (w == 0) ? bq : (w == 1) ? bk : bv;
  int tid = threadIdx.x;
  int wid = tid >> 6, lane = tid & 63;
  int wm = wid >> 1, wn = wid & 1;
  int r = lane & 15, g4 = lane >> 4;
  if (w == 2) {
    // transposed store: vt[((b*16+h)*64+d)][s], col = h*64+d, b = row>>11, s = row&2047
#pragma unroll
    for (int mi = 0; mi < 4; ++mi)
#pragma unroll
      for (int ni = 0; ni < 4; ++ni) {
        int col = n0 + wn * 64 + ni * 16 + r;
        float bcol = bias[col];
        int grow0 = m0 + wm * 64 + mi * 16 + g4 * 4;
        short4v pk;
        pk.x = f2bf(acc[mi][ni][0] + bcol);
        pk.y = f2bf(acc[mi][ni][1] + bcol);
        pk.z = f2bf(acc[mi][ni][2] + bcol);
        pk.w = f2bf(acc[mi][ni][3] + bcol);
        size_t vbase = ((size_t)(grow0 >> 11) * 1024 + col) * Ss + (grow0 & 2047);
        *(short4v*)(vt + vbase) = pk;
      }
  } else {
    short* dst = (w == 0) ? q : k;
    float qs = (w == 0) ? 0.125f : 1.0f;   // fold 1/sqrt(D) into Q
    // LDS-staged epilogue: full 128x128 tile, padded stride 136 shorts
    short* CT = (short*)LB;
    __syncthreads();                       // mainloop LDS reads done
#pragma unroll
    for (int mi = 0; mi < 4; ++mi)
#pragma unroll
      for (int ni = 0; ni < 4; ++ni) {
        int col = wn * 64 + ni * 16 + r;   // 0..127
        float bcol = bias[n0 + col];
#pragma unroll
        for (int i2 = 0; i2 < 4; ++i2) {
          int lrow = wm * 64 + mi * 16 + g4 * 4 + i2;   // 0..127
          CT[lrow * 136 + col] = f2bf((acc[mi][ni][i2] + bcol) * qs);
        }
      }
    __syncthreads();
#pragma unroll
    for (int it = 0; it < 8; ++it) {
      int slot = tid + 256 * it;           // 0..2047
      int lrow = slot >> 4, ccol = slot & 15;
      short8 vr = *(const short8*)&CT[lrow * 136 + ccol * 8];
      *(short8*)&dst[(size_t)(m0 + lrow) * Ee + n0 + ccol * 8] = vr;
    }
  }
}

// ---------------- Output GEMM + bias + residual (LDS-staged f32 epilogue) ----------------
__global__ __launch_bounds__(256) void out_gemm(const short* __restrict__ ctx,
                                                const short* __restrict__ wo,
                                                const float* __restrict__ bo,
                                                const float* __restrict__ xres,
                                                float* __restrict__ out) {
  __shared__ char LB[34816];               // mainloop 16KB; epilogue 64x132 f32 (33792B)
  short* As = (short*)LB;
  short* Bs = As + 4096;
  int bid = blockIdx.x;                    // 512 = 8*64
  int swz = (bid & 7) * 64 + (bid >> 3);
  int nb = swz & 7, mb = swz >> 3;
  int m0 = mb * 128, n0 = nb * 128;
  f32x4 acc[4][4];
#pragma unroll
  for (int i = 0; i < 4; ++i)
#pragma unroll
    for (int j = 0; j < 4; ++j) acc[i][j] = (f32x4){0.f, 0.f, 0.f, 0.f};
  gemm_main(ctx, wo, m0, n0, As, Bs, acc);
  int tid = threadIdx.x;
  int wid = tid >> 6, lane = tid & 63;
  int wm = wid >> 1, wn = wid & 1;
  int r = lane & 15, g4 = lane >> 4;
  float* CF = (float*)LB;
#pragma unroll
  for (int ph = 0; ph < 2; ++ph) {
    __syncthreads();                       // prior LDS use done
    if (wm == ph) {
#pragma unroll
      for (int mi = 0; mi < 4; ++mi)
#pragma unroll
        for (int ni = 0; ni < 4; ++ni) {
          int col = wn * 64 + ni * 16 + r;
          float bcol = bo[n0 + col];
#pragma unroll
          for (int i2 = 0; i2 < 4; ++i2) {
            int lrow = mi * 16 + g4 * 4 + i2;          // 0..63
            CF[lrow * 132 + col] = acc[mi][ni][i2] + bcol;
          }
        }
    }
    __syncthreads();
#pragma unroll
    for (int it = 0; it < 8; ++it) {
      int slot = tid + 256 * it;           // 0..2047
      int lrow = slot >> 5, c4 = slot & 31;
      float4 v = *(const float4*)&CF[lrow * 132 + c4 * 4];
      size_t off = (size_t)(m0 + ph * 64 + lrow) * Ee + n0 + c4 * 4;
      float4 xr4 = *(const float4*)&xres[off];
      v.x += xr4.x; v.y += xr4.y; v.z += xr4.z; v.w += xr4.w;
      *(float4*)&out[off] = v;
    }
  }
}

// ---------------- sliding-window attention, MFMA + swapped QK^T ----------------
// one wave per 16-row Q-tile; P-row lane-local (softmax in-lane); P normalized
// before LDS pack; V from transposed vt[b,h,d,s].
__global__ __launch_bounds__(256) void attn_mfma(const short* __restrict__ Q,
                                                 const short* __restrict__ K,
                                                 const short* __restrict__ vt,
                                                 short* __restrict__ ctx) {
  __shared__ short P_lds[4][16 * 296];     // per-wave [16 q][288 keys + pad]
  int bid = blockIdx.x;                    // 2048
  int swz = (bid & 7) * 256 + (bid >> 3);  // XCD-contiguous
  int bh = swz >> 5;                       // 64 (b,h) pairs
  int tq = swz & 31;
  int b = bh >> 4, h = bh & 15;
  int tid = threadIdx.x;
  int wid = tid >> 6, lane = tid & 63;
  int r = lane & 15, g4 = lane >> 4;
  int q0 = (tq * 4 + wid) * 16;
  short* pl = &P_lds[wid][0];
  f32x4 zero4 = {0.f, 0.f, 0.f, 0.f};

  // Q fragments (scale folded in at qkv epilogue)
  size_t qbase = ((size_t)(b * Ss + q0 + r)) * Ee + h * Dd + g4 * 8;
  short8 qf0 = *(const short8*)&Q[qbase];
  short8 qf1 = *(const short8*)&Q[qbase + 32];

  // ---- swapped QK^T: s = K_tile * Q_tile^T -> D[key][q], q = r lane-local ----
  int ktlo = (q0 >= 256) ? 0 : ((256 - q0) >> 4);
  f32x4 sc[17];
#pragma unroll
  for (int kt = 0; kt < 17; ++kt) {
    if (kt >= ktlo) {
      int rowk = q0 - 256 + kt * 16 + r;   // A-frag rows = keys
      size_t koff = ((size_t)(b * Ss + rowk)) * Ee + h * Dd + g4 * 8;
      short8 kf0 = *(const short8*)&K[koff];
      short8 kf1 = *(const short8*)&K[koff + 32];
      f32x4 s = __builtin_amdgcn_mfma_f32_16x16x32_bf16(kf0, qf0, zero4, 0, 0, 0);
      s = __builtin_amdgcn_mfma_f32_16x16x32_bf16(kf1, qf1, s, 0, 0, 0);
      // i = q0 + r (query, col); j = q0-256+16kt + 4g4+reg (key, row)
      int base = 256 + r - 16 * kt - 4 * g4;
#pragma unroll
      for (int reg = 0; reg < 4; ++reg) {
        int diff = base - reg;             // i - j
        sc[kt][reg] = ((unsigned)diff < 256u) ? s[reg] : -1e30f;
      }
    } else {
      sc[kt] = (f32x4){-1e30f, -1e30f, -1e30f, -1e30f};
    }
  }

  // ---- softmax: row split over 4 lanes (g4 copies), reduce via shfl 16/32 ----
  float mx = sc[0][0];
#pragma unroll
  for (int kt = 0; kt < 17; ++kt) {
    mx = fmaxf(mx, fmaxf(fmaxf(sc[kt][0], sc[kt][1]), fmaxf(sc[kt][2], sc[kt][3])));
  }
  mx = fmaxf(mx, __shfl_xor(mx, 16));
  mx = fmaxf(mx, __shfl_xor(mx, 32));
  float sum = 0.f;
#pragma unroll
  for (int kt = 0; kt < 17; ++kt)
#pragma unroll
    for (int reg = 0; reg < 4; ++reg) {
      float p = __expf(sc[kt][reg] - mx);
      sc[kt][reg] = p;
      sum += p;
    }
  sum += __shfl_xor(sum, 16);
  sum += __shfl_xor(sum, 32);
  float rl = 1.0f / sum;

  // ---- P*rl -> LDS packed b64 writes: pl[q=r][key 16kt+4g4+0..3] ----
#pragma unroll
  for (int kt = 0; kt < 17; ++kt) {
    short4v pk;
    pk.x = f2bf(sc[kt][0] * rl);
    pk.y = f2bf(sc[kt][1] * rl);
    pk.z = f2bf(sc[kt][2] * rl);
    pk.w = f2bf(sc[kt][3] * rl);
    *(short4v*)&pl[r * 296 + kt * 16 + 4 * g4] = pk;
  }
  {                                        // zero pad keys 272..287
    int zr = lane >> 2, zc = 272 + (lane & 3) * 4;
    *(short4v*)&pl[zr * 296 + zc] = (short4v){0, 0, 0, 0};
  }

  // ---- PV: 9 x 32-key steps, V from vt ----
  f32x4 acc[4];
#pragma unroll
  for (int nt = 0; nt < 4; ++nt) acc[nt] = zero4;
  size_t vtbase = ((size_t)(b * 1024 + h * Dd + r)) * Ss;
#pragma unroll
  for (int s8 = 0; s8 < 9; ++s8) {
    short8 pa = *(const short8*)&pl[r * 296 + s8 * 32 + g4 * 8];
    int tok0 = q0 - 256 + s8 * 32 + g4 * 8;
    tok0 = tok0 < 0 ? 0 : (tok0 > Ss - 8 ? Ss - 8 : tok0);  // P=0 masks OOB
#pragma unroll
    for (int nt = 0; nt < 4; ++nt) {
      short8 vf = *(const short8*)&vt[vtbase + (size_t)nt * 16 * Ss + tok0];
      acc[nt] = __builtin_amdgcn_mfma_f32_16x16x32_bf16(pa, vf, acc[nt], 0, 0, 0);
    }
  }

  // ---- epilogue: already normalized; stage in LDS, coalesced store ----
#pragma unroll
  for (int nt = 0; nt < 4; ++nt)
#pragma unroll
    for (int reg = 0; reg < 4; ++reg)
      pl[(4 * g4 + reg) * 72 + nt * 16 + r] = f2bf(acc[nt][reg]);
  int lr = lane >> 2, lc = (lane & 3) * 16;
  short8 o0 = *(const short8*)&pl[lr * 72 + lc];
  short8 o1 = *(const short8*)&pl[lr * 72 + lc + 8];
  size_t obase = ((size_t)(b * Ss + q0 + lr)) * Ee + h * Dd + lc;
  *(short8*)&ctx[obase] = o0;
  *(short8*)&ctx[obase + 8] = o1;
}

extern "C" void kernel_launch(void* const* d_in, const int* in_sizes, int n_in,
                              void* d_out, int out_size, void* d_ws, size_t ws_size,
                              hipStream_t stream) {
  const float* x    = (const float*)d_in[0];
  const float* ln_g = (const float*)d_in[1];
  const float* ln_b = (const float*)d_in[2];
  const float* w_q  = (const float*)d_in[3];
  const float* b_q  = (const float*)d_in[4];
  const float* w_k  = (const float*)d_in[5];
  const float* b_k  = (const float*)d_in[6];
  const float* w_v  = (const float*)d_in[7];
  const float* b_v  = (const float*)d_in[8];
  const float* w_o  = (const float*)d_in[9];
  const float* b_o  = (const float*)d_in[10];
  float* out = (float*)d_out;
  char* ws = (char*)d_ws;
  short* xn = (short*)(ws);                       // 16MB; reused as ctx after qkv
  short* qb = (short*)(ws + ((size_t)16 << 20));
  short* kb = (short*)(ws + ((size_t)32 << 20));
  short* vt = (short*)(ws + ((size_t)48 << 20));  // V transposed [B,H,D,S]
  short* wb = (short*)(ws + ((size_t)64 << 20));  // 4 x 2MB bf16 weights

  ln_kernel<<<Mrows, 256, 0, stream>>>(x, ln_g, ln_b, xn);
  wcvt_all<<<2048, 256, 0, stream>>>(w_q, w_k, w_v, w_o, wb);
  qkv_gemm<<<1536, 256, 0, stream>>>(xn, wb, b_q, b_k, b_v, qb, kb, vt);
  attn_mfma<<<2048, 256, 0, stream>>>(qb, kb, vt, xn /*ctx*/);
  out_gemm<<<512, 256, 0, stream>>>(xn /*ctx*/, wb + 3 * 1048576, b_o, x, out);
}